// Round 6
// baseline (1611.081 us; speedup 1.0000x reference)
//
#include <hip/hip_runtime.h>
#include <hip/hip_bf16.h>

#define D 128
#define BSH 7                      // 128 nodes per bucket
#define BMASK 127

typedef __attribute__((ext_vector_type(8))) short bf16x8;
typedef __attribute__((ext_vector_type(4))) float f32x4;
typedef unsigned short u16;
typedef unsigned int u32;

// fp32 -> bf16 round-to-nearest-even, bit-level
__device__ inline u16 f2bf(float f) {
    union { float f; u32 u; } v; v.f = f;
    u32 r = v.u + 0x7FFFu + ((v.u >> 16) & 1u);
    return (u16)(r >> 16);
}

// ---------------------------------------------------------------------------
// fp32 -> bf16 cast, 4 elements/thread
// ---------------------------------------------------------------------------
__global__ void cast_kernel(const float* __restrict__ in, u16* __restrict__ out, int n4) {
    int i = blockIdx.x * blockDim.x + threadIdx.x;
    if (i < n4) {
        float4 v = *(const float4*)(in + (size_t)i * 4);
        u32 lo = (u32)f2bf(v.x) | ((u32)f2bf(v.y) << 16);
        u32 hi = (u32)f2bf(v.z) | ((u32)f2bf(v.w) << 16);
        *(uint2*)(out + (size_t)i * 4) = make_uint2(lo, hi);
    }
}

// ---------------------------------------------------------------------------
// Bucketed edge partition. Bucket = 128 consecutive src nodes (782 buckets).
// Stage 1: per-block LDS histogram -> one global atomic per (block,bucket).
// ---------------------------------------------------------------------------
__global__ void bucket_count(const int* __restrict__ src, int* __restrict__ bucketCount,
                             int E, int nbuk) {
    __shared__ int cnt[1024];
    for (int i = threadIdx.x; i < nbuk; i += blockDim.x) cnt[i] = 0;
    __syncthreads();
    int stride = gridDim.x * blockDim.x;
    for (int i = blockIdx.x * blockDim.x + threadIdx.x; i < E; i += stride)
        atomicAdd(&cnt[src[i] >> BSH], 1);
    __syncthreads();
    for (int i = threadIdx.x; i < nbuk; i += blockDim.x)
        if (cnt[i]) atomicAdd(&bucketCount[i], cnt[i]);
}

// Stage 2: exclusive scan of bucket counts (nbuk <= 1024). One block.
__global__ void bucket_scan(const int* __restrict__ bucketCount, int* __restrict__ bucketBase,
                            int* __restrict__ bucketCursor, int nbuk, int E) {
    __shared__ int s[1024];
    int t = threadIdx.x;
    s[t] = (t < nbuk) ? bucketCount[t] : 0;
    __syncthreads();
    for (int off = 1; off < 1024; off <<= 1) {
        int v = (t >= off) ? s[t - off] : 0;
        __syncthreads();
        s[t] += v;
        __syncthreads();
    }
    if (t < nbuk) {
        int excl = (t == 0) ? 0 : s[t - 1];
        bucketBase[t] = excl;
        bucketCursor[t] = excl;
    }
    if (t == 0) bucketBase[nbuk] = E;
}

// Stage 3: partition edges into buckets (unordered within bucket — consumer
// accumulates, so no per-node CSR needed). Record: .x = dst | srcLocal<<17
// (dst < 2^17), .y = weight bits.
__global__ void partition_kernel(const int* __restrict__ src, const int* __restrict__ dst,
                                 const float* __restrict__ w, int* __restrict__ bucketCursor,
                                 uint2* __restrict__ temp, int E, int nbuk) {
    __shared__ int cnt[1024];
    __shared__ int base[1024];
    int per = (E + gridDim.x - 1) / gridDim.x;
    int lo = blockIdx.x * per;
    int hi = min(E, lo + per);
    for (int i = threadIdx.x; i < nbuk; i += blockDim.x) cnt[i] = 0;
    __syncthreads();
    for (int i = lo + threadIdx.x; i < hi; i += blockDim.x)
        atomicAdd(&cnt[src[i] >> BSH], 1);
    __syncthreads();
    for (int i = threadIdx.x; i < nbuk; i += blockDim.x)
        base[i] = cnt[i] ? atomicAdd(&bucketCursor[i], cnt[i]) : 0;
    __syncthreads();
    for (int i = threadIdx.x; i < nbuk; i += blockDim.x) cnt[i] = 0;
    __syncthreads();
    for (int i = lo + threadIdx.x; i < hi; i += blockDim.x) {
        int s = src[i];
        int b = s >> BSH;
        int off = atomicAdd(&cnt[b], 1);
        temp[base[b] + off] =
            make_uint2((u32)dst[i] | ((u32)(s & BMASK) << 17), __float_as_uint(w[i]));
    }
}

// ---------------------------------------------------------------------------
// Bucket aggregation: one block per 128-node bucket. Accumulates weighted
// neighbor rows into a 64KB LDS accumulator (ds_add_f32), then divides by
// wsum and writes bf16. Edges stripe evenly over 8 waves (no per-node
// imbalance); 4 gathers in flight per wave.
// LDS column permutation: feature f=2i -> col i, f=2i+1 -> col 64+i, so each
// 64-lane atomic covers 64 consecutive floats (2-way bank alias = free).
// ---------------------------------------------------------------------------
__global__ void __launch_bounds__(512, 2)
bucket_aggregate(const u16* __restrict__ feat,
                 const uint2* __restrict__ temp,
                 const int* __restrict__ bucketBase,
                 u16* __restrict__ neigh, int N) {
    __shared__ float accS[128][128];   // 64 KB
    __shared__ float wsumS[128];

    const int b = blockIdx.x;
    const int t = threadIdx.x;
    const int wave = t >> 6;    // 0..7
    const int lane = t & 63;

    float* af = &accS[0][0];
    for (int i = t; i < 128 * 128; i += 512) af[i] = 0.f;
    if (t < 128) wsumS[t] = 0.f;
    __syncthreads();

    const int lo = bucketBase[b];
    const int hi = bucketBase[b + 1];

    int j0 = lo + wave * 4;
    for (; j0 + 4 <= hi; j0 += 32) {
        uint2 e0 = temp[j0], e1 = temp[j0 + 1], e2 = temp[j0 + 2], e3 = temp[j0 + 3];
        u32 u0 = *(const u32*)(feat + (size_t)(e0.x & 0x1FFFFu) * D + lane * 2);
        u32 u1 = *(const u32*)(feat + (size_t)(e1.x & 0x1FFFFu) * D + lane * 2);
        u32 u2 = *(const u32*)(feat + (size_t)(e2.x & 0x1FFFFu) * D + lane * 2);
        u32 u3 = *(const u32*)(feat + (size_t)(e3.x & 0x1FFFFu) * D + lane * 2);
        float w0 = __uint_as_float(e0.y), w1 = __uint_as_float(e1.y);
        float w2 = __uint_as_float(e2.y), w3 = __uint_as_float(e3.y);
        int s0 = e0.x >> 17, s1 = e1.x >> 17, s2 = e2.x >> 17, s3 = e3.x >> 17;
        atomicAdd(&accS[s0][lane],      __uint_as_float(u0 << 16) * w0);
        atomicAdd(&accS[s0][64 + lane], __uint_as_float(u0 & 0xFFFF0000u) * w0);
        atomicAdd(&accS[s1][lane],      __uint_as_float(u1 << 16) * w1);
        atomicAdd(&accS[s1][64 + lane], __uint_as_float(u1 & 0xFFFF0000u) * w1);
        atomicAdd(&accS[s2][lane],      __uint_as_float(u2 << 16) * w2);
        atomicAdd(&accS[s2][64 + lane], __uint_as_float(u2 & 0xFFFF0000u) * w2);
        atomicAdd(&accS[s3][lane],      __uint_as_float(u3 << 16) * w3);
        atomicAdd(&accS[s3][64 + lane], __uint_as_float(u3 & 0xFFFF0000u) * w3);
        if (lane == 0) atomicAdd(&wsumS[s0], w0 + w1 + w2 + w3 - w1 - w2 - w3), // keep simple below
            (void)0;
        if (lane == 0) {
            // per-edge wsum (nodes differ): add individually
            atomicAdd(&wsumS[s1], w1);
            atomicAdd(&wsumS[s2], w2);
            atomicAdd(&wsumS[s3], w3);
        }
    }
    // tail (at most one wave has a partial quad)
    for (int j = j0; j < min(j0 + 4, hi); ++j) {
        uint2 e0 = temp[j];
        u32 u0 = *(const u32*)(feat + (size_t)(e0.x & 0x1FFFFu) * D + lane * 2);
        float w0 = __uint_as_float(e0.y);
        int s0 = e0.x >> 17;
        atomicAdd(&accS[s0][lane],      __uint_as_float(u0 << 16) * w0);
        atomicAdd(&accS[s0][64 + lane], __uint_as_float(u0 & 0xFFFF0000u) * w0);
        if (lane == 0) atomicAdd(&wsumS[s0], w0);
    }
    __syncthreads();

    // Write-out: 128 rows x 64 u32 words; wave handles one row per iter.
    const int nodeBase = b << BSH;
    for (int iter = 0; iter < 16; ++iter) {
        int w = iter * 512 + t;          // 0..8191
        int row = w >> 6;                // 0..127 (constant within a wave)
        int j = w & 63;
        int gnode = nodeBase + row;
        if (gnode < N) {
            float iw = 1.0f / fmaxf(wsumS[row], 1e-12f);
            float v0 = accS[row][j] * iw;        // feature 2j
            float v1 = accS[row][64 + j] * iw;   // feature 2j+1
            u32 o = (u32)f2bf(v0) | ((u32)f2bf(v1) << 16);
            *(u32*)(neigh + (size_t)gnode * D + j * 2) = o;
        }
    }
}

// ---------------------------------------------------------------------------
// Fused SAGE GEMM, all-bf16 inputs. 256x128 tile/block, 512 threads (8 waves).
// A[r][k] = axb[r][k] (k<128) else aneigh[r][k-128]. Wb is bf16 [128][256].
// Register-prefetch double buffering.
// NORM=false: store bf16 h.  NORM=true: row-L2-normalize in-epilogue, store f32.
// ---------------------------------------------------------------------------
template <bool NORM>
__global__ void __launch_bounds__(512, 4)
sage_gemm(const u16* __restrict__ axb,
          const u16* __restrict__ aneigh,
          const u16* __restrict__ Wb,      // [128][256] bf16
          const float* __restrict__ bias,  // [128]
          u16* __restrict__ outB,          // NORM=false
          float* __restrict__ outF,        // NORM=true
          int n) {
    __shared__ short As[256][72];   // +8 pad keeps aliasing 2-way (free)
    __shared__ short Bs[128][72];

    const int row0 = blockIdx.x * 256;
    const int tid  = threadIdx.x;
    const int wave = tid >> 6;   // 0..7
    const int lane = tid & 63;
    const int quad = lane >> 4;
    const int l16  = lane & 15;

    f32x4 acc[2][8];
#pragma unroll
    for (int rt = 0; rt < 2; ++rt)
#pragma unroll
        for (int c = 0; c < 8; ++c)
            acc[rt][c] = (f32x4){0.f, 0.f, 0.f, 0.f};

    uint4 pa[4], pb[2];
    auto loadTile = [&](int kc) {
        const u16* asrc = (kc >= 2) ? aneigh : axb;
        const int cbase = (kc & 1) * 64;
#pragma unroll
        for (int i = 0; i < 4; ++i) {
            int e = i * 512 + tid;
            int r = e >> 3;
            int c8 = (e & 7) * 8;
            int row = row0 + r;
            if (row >= n) row = n - 1;       // clamp; garbage rows never stored
            pa[i] = *(const uint4*)(asrc + (size_t)row * D + cbase + c8);
        }
#pragma unroll
        for (int i = 0; i < 2; ++i) {
            int e = i * 512 + tid;
            int r = e >> 3;
            int c8 = (e & 7) * 8;
            pb[i] = *(const uint4*)(Wb + (size_t)r * 256 + kc * 64 + c8);
        }
    };

    loadTile(0);
#pragma unroll
    for (int kc = 0; kc < 4; ++kc) {
#pragma unroll
        for (int i = 0; i < 4; ++i) {
            int e = i * 512 + tid;
            *(uint4*)(&As[e >> 3][(e & 7) * 8]) = pa[i];
        }
#pragma unroll
        for (int i = 0; i < 2; ++i) {
            int e = i * 512 + tid;
            *(uint4*)(&Bs[e >> 3][(e & 7) * 8]) = pb[i];
        }
        __syncthreads();
        if (kc < 3) loadTile(kc + 1);   // overlaps with MFMA below

#pragma unroll
        for (int ks = 0; ks < 2; ++ks) {
            const int koff = ks * 32 + quad * 8;
            bf16x8 a0 = *(const bf16x8*)&As[wave * 32 + l16][koff];
            bf16x8 a1 = *(const bf16x8*)&As[wave * 32 + 16 + l16][koff];
#pragma unroll
            for (int c = 0; c < 8; ++c) {
                bf16x8 b = *(const bf16x8*)&Bs[c * 16 + l16][koff];
                acc[0][c] = __builtin_amdgcn_mfma_f32_16x16x32_bf16(a0, b, acc[0][c], 0, 0, 0);
                acc[1][c] = __builtin_amdgcn_mfma_f32_16x16x32_bf16(a1, b, acc[1][c], 0, 0, 0);
            }
        }
        __syncthreads();
    }

    // Epilogue. C/D layout: col=lane&15, row=quad*4+reg.
    float bvals[8];
#pragma unroll
    for (int c = 0; c < 8; ++c) bvals[c] = bias[c * 16 + l16];

#pragma unroll
    for (int rt = 0; rt < 2; ++rt) {
#pragma unroll
        for (int reg = 0; reg < 4; ++reg) {
            int row = row0 + wave * 32 + rt * 16 + quad * 4 + reg;
            if (row >= n) continue;
            float v[8];
#pragma unroll
            for (int c = 0; c < 8; ++c)
                v[c] = fmaxf(acc[rt][c][reg] + bvals[c], 0.0f);
            if (NORM) {
                float ss = 0.f;
#pragma unroll
                for (int c = 0; c < 8; ++c) ss += v[c] * v[c];
                ss += __shfl_xor(ss, 1);
                ss += __shfl_xor(ss, 2);
                ss += __shfl_xor(ss, 4);
                ss += __shfl_xor(ss, 8);
                float inv = 1.0f / fmaxf(sqrtf(ss), 1e-12f);
                float* orow = outF + (size_t)row * D;
#pragma unroll
                for (int c = 0; c < 8; ++c)
                    orow[c * 16 + l16] = v[c] * inv;
            } else {
                u16* orow = outB + (size_t)row * D;
#pragma unroll
                for (int c = 0; c < 8; ++c)
                    orow[c * 16 + l16] = f2bf(v[c]);
            }
        }
    }
}

extern "C" void kernel_launch(void* const* d_in, const int* in_sizes, int n_in,
                              void* d_out, int out_size, void* d_ws, size_t ws_size,
                              hipStream_t stream) {
    const float* x  = (const float*)d_in[0];
    const int*   ei = (const int*)d_in[1];   // [2, E]: row 0 = src, row 1 = dst
    const float* ew = (const float*)d_in[2];
    const float* W1 = (const float*)d_in[3];
    const float* b1 = (const float*)d_in[4];
    const float* W2 = (const float*)d_in[5];
    const float* b2 = (const float*)d_in[6];
    float* out = (float*)d_out;

    const int E = in_sizes[2];
    const int N = in_sizes[0] / D;
    const int nbuk = (N + BMASK) >> BSH;     // 782 for N=100000 (<=1024 required)

    const int* src = ei;
    const int* dst = ei + E;

    // workspace layout
    char* p = (char*)d_ws;
    auto alloc = [&](size_t bytes) { char* r = p; p += (bytes + 255) & ~(size_t)255; return r; };
    u16*   xb      = (u16*)  alloc((size_t)N * D * sizeof(u16));   // 25.6 MB
    u16*   hB      = (u16*)  alloc((size_t)N * D * sizeof(u16));   // 25.6 MB
    u16*   neighB  = (u16*)  alloc((size_t)N * D * sizeof(u16));   // 25.6 MB
    uint2* temp    = (uint2*)alloc((size_t)E * sizeof(uint2));     // 6.4 MB
    u16*   Wb1     = (u16*)  alloc((size_t)D * 2 * D * sizeof(u16));
    u16*   Wb2     = (u16*)  alloc((size_t)D * 2 * D * sizeof(u16));
    int*   bCount  = (int*)  alloc((size_t)(nbuk + 1) * sizeof(int));
    int*   bBase   = (int*)  alloc((size_t)(nbuk + 1) * sizeof(int));
    int*   bCursor = (int*)  alloc((size_t)(nbuk + 1) * sizeof(int));

    const int gemmGrid = (N + 255) / 256;
    const int n4 = N * D / 4;
    const int w4 = D * 2 * D / 4;   // 8192

    // ---- Bucket partition + casts ----
    hipMemsetAsync(bCount, 0, (size_t)nbuk * sizeof(int), stream);
    bucket_count    <<<256, 256, 0, stream>>>(src, bCount, E, nbuk);
    bucket_scan     <<<1, 1024, 0, stream>>>(bCount, bBase, bCursor, nbuk, E);
    partition_kernel<<<256, 256, 0, stream>>>(src, dst, ew, bCursor, temp, E, nbuk);
    cast_kernel     <<<(n4 + 255) / 256, 256, 0, stream>>>(x, xb, n4);
    cast_kernel     <<<(w4 + 255) / 256, 256, 0, stream>>>(W1, Wb1, w4);
    cast_kernel     <<<(w4 + 255) / 256, 256, 0, stream>>>(W2, Wb2, w4);

    // ---- Layer 1 ----
    bucket_aggregate<<<nbuk, 512, 0, stream>>>(xb, temp, bBase, neighB, N);
    sage_gemm<false><<<gemmGrid, 512, 0, stream>>>(xb, neighB, Wb1, b1, hB, nullptr, N);

    // ---- Layer 2 (normalize fused into epilogue) ----
    bucket_aggregate<<<nbuk, 512, 0, stream>>>(hB, temp, bBase, neighB, N);
    sage_gemm<true><<<gemmGrid, 512, 0, stream>>>(hB, neighB, Wb2, b2, nullptr, out, N);
}

// Round 7
// 357.011 us; speedup vs baseline: 4.5127x; 4.5127x over previous
//
#include <hip/hip_runtime.h>
#include <hip/hip_bf16.h>

#define D 128
#define BSH 8                      // 256 nodes per bucket
#define BMASK 255

typedef __attribute__((ext_vector_type(8))) short bf16x8;
typedef __attribute__((ext_vector_type(4))) float f32x4;
typedef unsigned short u16;
typedef unsigned int u32;

// fp32 -> bf16 round-to-nearest-even, bit-level
__device__ inline u16 f2bf(float f) {
    union { float f; u32 u; } v; v.f = f;
    u32 r = v.u + 0x7FFFu + ((v.u >> 16) & 1u);
    return (u16)(r >> 16);
}

// ---------------------------------------------------------------------------
// fp32 -> bf16 cast of three concatenated arrays in one launch.
// ---------------------------------------------------------------------------
__global__ void cast3_kernel(const float* __restrict__ a, const float* __restrict__ b,
                             const float* __restrict__ c, u16* __restrict__ oa,
                             u16* __restrict__ ob, u16* __restrict__ oc,
                             int na4, int nw4) {
    int i = blockIdx.x * blockDim.x + threadIdx.x;
    const float* in; u16* out; int k;
    if (i < na4)                { in = a; out = oa; k = i; }
    else if (i < na4 + nw4)     { in = b; out = ob; k = i - na4; }
    else if (i < na4 + 2 * nw4) { in = c; out = oc; k = i - na4 - nw4; }
    else return;
    float4 v = *(const float4*)(in + (size_t)k * 4);
    u32 lo = (u32)f2bf(v.x) | ((u32)f2bf(v.y) << 16);
    u32 hi = (u32)f2bf(v.z) | ((u32)f2bf(v.w) << 16);
    *(uint2*)(out + (size_t)k * 4) = make_uint2(lo, hi);
}

// ---------------------------------------------------------------------------
// Two-level bucketed CSR build. Bucket = 256 consecutive src nodes.
// ---------------------------------------------------------------------------
__global__ void bucket_count(const int* __restrict__ src, int* __restrict__ bucketCount,
                             int E, int nbuk) {
    __shared__ int cnt[1024];
    for (int i = threadIdx.x; i < nbuk; i += blockDim.x) cnt[i] = 0;
    __syncthreads();
    int stride = gridDim.x * blockDim.x;
    for (int i = blockIdx.x * blockDim.x + threadIdx.x; i < E; i += stride)
        atomicAdd(&cnt[src[i] >> BSH], 1);
    __syncthreads();
    for (int i = threadIdx.x; i < nbuk; i += blockDim.x)
        if (cnt[i]) atomicAdd(&bucketCount[i], cnt[i]);
}

__global__ void bucket_scan(const int* __restrict__ bucketCount, int* __restrict__ bucketBase,
                            int* __restrict__ bucketCursor, int nbuk, int E) {
    __shared__ int s[1024];
    int t = threadIdx.x;
    s[t] = (t < nbuk) ? bucketCount[t] : 0;
    __syncthreads();
    for (int off = 1; off < 1024; off <<= 1) {
        int v = (t >= off) ? s[t - off] : 0;
        __syncthreads();
        s[t] += v;
        __syncthreads();
    }
    if (t < nbuk) {
        int excl = (t == 0) ? 0 : s[t - 1];
        bucketBase[t] = excl;
        bucketCursor[t] = excl;
    }
    if (t == 0) bucketBase[nbuk] = E;
}

// Record: .x = dst | srcLocal<<17 (dst < 2^17), .y = weight bits.
__global__ void partition_kernel(const int* __restrict__ src, const int* __restrict__ dst,
                                 const float* __restrict__ w, int* __restrict__ bucketCursor,
                                 uint2* __restrict__ temp, int E, int nbuk) {
    __shared__ int cnt[1024];
    __shared__ int base[1024];
    int per = (E + gridDim.x - 1) / gridDim.x;
    int lo = blockIdx.x * per;
    int hi = min(E, lo + per);
    for (int i = threadIdx.x; i < nbuk; i += blockDim.x) cnt[i] = 0;
    __syncthreads();
    for (int i = lo + threadIdx.x; i < hi; i += blockDim.x)
        atomicAdd(&cnt[src[i] >> BSH], 1);
    __syncthreads();
    for (int i = threadIdx.x; i < nbuk; i += blockDim.x)
        base[i] = cnt[i] ? atomicAdd(&bucketCursor[i], cnt[i]) : 0;
    __syncthreads();
    for (int i = threadIdx.x; i < nbuk; i += blockDim.x) cnt[i] = 0;
    __syncthreads();
    for (int i = lo + threadIdx.x; i < hi; i += blockDim.x) {
        int s = src[i];
        int b = s >> BSH;
        int off = atomicAdd(&cnt[b], 1);
        temp[base[b] + off] =
            make_uint2((u32)dst[i] | ((u32)(s & BMASK) << 17), __float_as_uint(w[i]));
    }
}

// Per-bucket CSR finalize (int LDS atomics = native ds_add, fast).
__global__ void bucket_csr(const uint2* __restrict__ temp, const int* __restrict__ bucketBase,
                           int* __restrict__ rowptr, uint2* __restrict__ edge,
                           int N, int E) {
    int b = blockIdx.x;
    int lo = bucketBase[b], hi = bucketBase[b + 1];
    int t = threadIdx.x;
    __shared__ int deg_l[256];
    __shared__ int sc[256];
    __shared__ int cur[256];
    deg_l[t] = 0;
    __syncthreads();
    for (int i = lo + t; i < hi; i += 256)
        atomicAdd(&deg_l[temp[i].x >> 17], 1);
    __syncthreads();
    sc[t] = deg_l[t];
    __syncthreads();
    for (int off = 1; off < 256; off <<= 1) {
        int v = (t >= off) ? sc[t - off] : 0;
        __syncthreads();
        sc[t] += v;
        __syncthreads();
    }
    int excl = (t == 0) ? 0 : sc[t - 1];
    int gnode = b * 256 + t;
    if (gnode < N) rowptr[gnode] = lo + excl;
    if (b == 0 && t == 0) rowptr[N] = E;
    cur[t] = excl;
    __syncthreads();
    for (int i = lo + t; i < hi; i += 256) {
        uint2 r = temp[i];                     // L2-hot
        int p = atomicAdd(&cur[r.x >> 17], 1);
        edge[lo + p] = make_uint2(r.x & 0x1FFFFu, r.y);
    }
}

// ---------------------------------------------------------------------------
// Gather aggregation (bf16): one wave per 2 nodes (imbalance averaging).
// neigh[node] = bf16( sum_e w_e*feat[dst_e] / max(sum_e w_e, eps) )
// 32-bit byte-offset addressing: dst*256 + lane*4 (< 2^25).
// ---------------------------------------------------------------------------
__global__ void aggregate_kernel(const u16* __restrict__ feat,
                                 const int* __restrict__ rowptr,
                                 const uint2* __restrict__ edge,
                                 u16* __restrict__ neigh, int n) {
    const char* fb = (const char*)feat;
    int wv = blockIdx.x * 4 + (threadIdx.x >> 6);
    int lane = threadIdx.x & 63;
    int node0 = wv * 2;
    if (node0 >= n) return;
    const u32 lo4 = (u32)lane * 4u;
    int nend = min(node0 + 2, n);
    for (int node = node0; node < nend; ++node) {
        int beg = rowptr[node];
        int end = rowptr[node + 1];
        float ax = 0.f, ay = 0.f, ws = 0.f;
        int j = beg;
        for (; j + 3 < end; j += 4) {   // 4 gathers in flight
            uint2 e0 = edge[j], e1 = edge[j + 1], e2 = edge[j + 2], e3 = edge[j + 3];
            float w0 = __uint_as_float(e0.y), w1 = __uint_as_float(e1.y);
            float w2 = __uint_as_float(e2.y), w3 = __uint_as_float(e3.y);
            u32 u0 = *(const u32*)(fb + e0.x * 256u + lo4);
            u32 u1 = *(const u32*)(fb + e1.x * 256u + lo4);
            u32 u2 = *(const u32*)(fb + e2.x * 256u + lo4);
            u32 u3 = *(const u32*)(fb + e3.x * 256u + lo4);
            ax += __uint_as_float(u0 << 16) * w0 + __uint_as_float(u1 << 16) * w1
                + __uint_as_float(u2 << 16) * w2 + __uint_as_float(u3 << 16) * w3;
            ay += __uint_as_float(u0 & 0xFFFF0000u) * w0 + __uint_as_float(u1 & 0xFFFF0000u) * w1
                + __uint_as_float(u2 & 0xFFFF0000u) * w2 + __uint_as_float(u3 & 0xFFFF0000u) * w3;
            ws += w0 + w1 + w2 + w3;
        }
        for (; j < end; ++j) {
            uint2 e0 = edge[j];
            float w0 = __uint_as_float(e0.y);
            u32 u0 = *(const u32*)(fb + e0.x * 256u + lo4);
            ax += __uint_as_float(u0 << 16) * w0;
            ay += __uint_as_float(u0 & 0xFFFF0000u) * w0;
            ws += w0;
        }
        float inv = 1.0f / fmaxf(ws, 1e-12f);
        u32 o = (u32)f2bf(ax * inv) | ((u32)f2bf(ay * inv) << 16);
        *(u32*)(neigh + (size_t)node * D + lane * 2) = o;
    }
}

// ---------------------------------------------------------------------------
// Fused SAGE GEMM, all-bf16 inputs. 256x128 tile/block, 512 threads (8 waves).
// Register-prefetch double buffering. (R5-identical.)
// ---------------------------------------------------------------------------
template <bool NORM>
__global__ void __launch_bounds__(512, 4)
sage_gemm(const u16* __restrict__ axb,
          const u16* __restrict__ aneigh,
          const u16* __restrict__ Wb,      // [128][256] bf16
          const float* __restrict__ bias,  // [128]
          u16* __restrict__ outB,          // NORM=false
          float* __restrict__ outF,        // NORM=true
          int n) {
    __shared__ short As[256][72];   // +8 pad keeps aliasing 2-way (free)
    __shared__ short Bs[128][72];

    const int row0 = blockIdx.x * 256;
    const int tid  = threadIdx.x;
    const int wave = tid >> 6;
    const int lane = tid & 63;
    const int quad = lane >> 4;
    const int l16  = lane & 15;

    f32x4 acc[2][8];
#pragma unroll
    for (int rt = 0; rt < 2; ++rt)
#pragma unroll
        for (int c = 0; c < 8; ++c)
            acc[rt][c] = (f32x4){0.f, 0.f, 0.f, 0.f};

    uint4 pa[4], pb[2];
    auto loadTile = [&](int kc) {
        const u16* asrc = (kc >= 2) ? aneigh : axb;
        const int cbase = (kc & 1) * 64;
#pragma unroll
        for (int i = 0; i < 4; ++i) {
            int e = i * 512 + tid;
            int r = e >> 3;
            int c8 = (e & 7) * 8;
            int row = row0 + r;
            if (row >= n) row = n - 1;       // clamp; garbage rows never stored
            pa[i] = *(const uint4*)(asrc + (size_t)row * D + cbase + c8);
        }
#pragma unroll
        for (int i = 0; i < 2; ++i) {
            int e = i * 512 + tid;
            int r = e >> 3;
            int c8 = (e & 7) * 8;
            pb[i] = *(const uint4*)(Wb + (size_t)r * 256 + kc * 64 + c8);
        }
    };

    loadTile(0);
#pragma unroll
    for (int kc = 0; kc < 4; ++kc) {
#pragma unroll
        for (int i = 0; i < 4; ++i) {
            int e = i * 512 + tid;
            *(uint4*)(&As[e >> 3][(e & 7) * 8]) = pa[i];
        }
#pragma unroll
        for (int i = 0; i < 2; ++i) {
            int e = i * 512 + tid;
            *(uint4*)(&Bs[e >> 3][(e & 7) * 8]) = pb[i];
        }
        __syncthreads();
        if (kc < 3) loadTile(kc + 1);   // overlaps with MFMA below

#pragma unroll
        for (int ks = 0; ks < 2; ++ks) {
            const int koff = ks * 32 + quad * 8;
            bf16x8 a0 = *(const bf16x8*)&As[wave * 32 + l16][koff];
            bf16x8 a1 = *(const bf16x8*)&As[wave * 32 + 16 + l16][koff];
#pragma unroll
            for (int c = 0; c < 8; ++c) {
                bf16x8 b = *(const bf16x8*)&Bs[c * 16 + l16][koff];
                acc[0][c] = __builtin_amdgcn_mfma_f32_16x16x32_bf16(a0, b, acc[0][c], 0, 0, 0);
                acc[1][c] = __builtin_amdgcn_mfma_f32_16x16x32_bf16(a1, b, acc[1][c], 0, 0, 0);
            }
        }
        __syncthreads();
    }

    // Epilogue. C/D layout: col=lane&15, row=quad*4+reg.
    float bvals[8];
#pragma unroll
    for (int c = 0; c < 8; ++c) bvals[c] = bias[c * 16 + l16];

#pragma unroll
    for (int rt = 0; rt < 2; ++rt) {
#pragma unroll
        for (int reg = 0; reg < 4; ++reg) {
            int row = row0 + wave * 32 + rt * 16 + quad * 4 + reg;
            if (row >= n) continue;
            float v[8];
#pragma unroll
            for (int c = 0; c < 8; ++c)
                v[c] = fmaxf(acc[rt][c][reg] + bvals[c], 0.0f);
            if (NORM) {
                float ss = 0.f;
#pragma unroll
                for (int c = 0; c < 8; ++c) ss += v[c] * v[c];
                ss += __shfl_xor(ss, 1);
                ss += __shfl_xor(ss, 2);
                ss += __shfl_xor(ss, 4);
                ss += __shfl_xor(ss, 8);
                float inv = 1.0f / fmaxf(sqrtf(ss), 1e-12f);
                float* orow = outF + (size_t)row * D;
#pragma unroll
                for (int c = 0; c < 8; ++c)
                    orow[c * 16 + l16] = v[c] * inv;
            } else {
                u16* orow = outB + (size_t)row * D;
#pragma unroll
                for (int c = 0; c < 8; ++c)
                    orow[c * 16 + l16] = f2bf(v[c]);
            }
        }
    }
}

extern "C" void kernel_launch(void* const* d_in, const int* in_sizes, int n_in,
                              void* d_out, int out_size, void* d_ws, size_t ws_size,
                              hipStream_t stream) {
    const float* x  = (const float*)d_in[0];
    const int*   ei = (const int*)d_in[1];   // [2, E]: row 0 = src, row 1 = dst
    const float* ew = (const float*)d_in[2];
    const float* W1 = (const float*)d_in[3];
    const float* b1 = (const float*)d_in[4];
    const float* W2 = (const float*)d_in[5];
    const float* b2 = (const float*)d_in[6];
    float* out = (float*)d_out;

    const int E = in_sizes[2];
    const int N = in_sizes[0] / D;
    const int nbuk = (N + BMASK) >> BSH;     // 391 for N=100000

    const int* src = ei;
    const int* dst = ei + E;

    // workspace layout
    char* p = (char*)d_ws;
    auto alloc = [&](size_t bytes) { char* r = p; p += (bytes + 255) & ~(size_t)255; return r; };
    u16*   xb      = (u16*)  alloc((size_t)N * D * sizeof(u16));   // 25.6 MB
    u16*   hB      = (u16*)  alloc((size_t)N * D * sizeof(u16));   // 25.6 MB
    u16*   neighB  = (u16*)  alloc((size_t)N * D * sizeof(u16));   // 25.6 MB
    uint2* edge    = (uint2*)alloc((size_t)E * sizeof(uint2));     // 6.4 MB
    uint2* temp    = (uint2*)alloc((size_t)E * sizeof(uint2));     // 6.4 MB
    u16*   Wb1     = (u16*)  alloc((size_t)D * 2 * D * sizeof(u16));
    u16*   Wb2     = (u16*)  alloc((size_t)D * 2 * D * sizeof(u16));
    int*   rowptr  = (int*)  alloc((size_t)(N + 1) * sizeof(int));
    int*   bCount  = (int*)  alloc((size_t)(nbuk + 1) * sizeof(int));
    int*   bBase   = (int*)  alloc((size_t)(nbuk + 1) * sizeof(int));
    int*   bCursor = (int*)  alloc((size_t)(nbuk + 1) * sizeof(int));

    const int gemmGrid = (N + 255) / 256;
    const int n4 = N * D / 4;
    const int w4 = D * 2 * D / 4;   // 8192
    const int castTotal = n4 + 2 * w4;
    const int aggGrid = ((N + 1) / 2 + 3) / 4;

    // ---- Bucketed CSR build + casts ----
    hipMemsetAsync(bCount, 0, (size_t)nbuk * sizeof(int), stream);
    bucket_count    <<<256, 256, 0, stream>>>(src, bCount, E, nbuk);
    bucket_scan     <<<1, 1024, 0, stream>>>(bCount, bBase, bCursor, nbuk, E);
    partition_kernel<<<256, 256, 0, stream>>>(src, dst, ew, bCursor, temp, E, nbuk);
    bucket_csr      <<<nbuk, 256, 0, stream>>>(temp, bBase, rowptr, edge, N, E);
    cast3_kernel    <<<(castTotal + 255) / 256, 256, 0, stream>>>(x, W1, W2, xb, Wb1, Wb2, n4, w4);

    // ---- Layer 1 ----
    aggregate_kernel<<<aggGrid, 256, 0, stream>>>(xb, rowptr, edge, neighB, N);
    sage_gemm<false><<<gemmGrid, 512, 0, stream>>>(xb, neighB, Wb1, b1, hB, nullptr, N);

    // ---- Layer 2 (normalize fused into epilogue) ----
    aggregate_kernel<<<aggGrid, 256, 0, stream>>>(hB, rowptr, edge, neighB, N);
    sage_gemm<true><<<gemmGrid, 512, 0, stream>>>(hB, neighB, Wb2, b2, nullptr, out, N);
}

// Round 8
// 323.500 us; speedup vs baseline: 4.9802x; 1.1036x over previous
//
#include <hip/hip_runtime.h>
#include <hip/hip_bf16.h>

#define D 128
#define BSH 8                      // 256 nodes per bucket
#define BMASK 255

typedef __attribute__((ext_vector_type(8))) short bf16x8;
typedef __attribute__((ext_vector_type(4))) float f32x4;
typedef unsigned short u16;
typedef unsigned int u32;

// fp32 -> bf16 round-to-nearest-even, bit-level
__device__ inline u16 f2bf(float f) {
    union { float f; u32 u; } v; v.f = f;
    u32 r = v.u + 0x7FFFu + ((v.u >> 16) & 1u);
    return (u16)(r >> 16);
}

// ---------------------------------------------------------------------------
// fp32 -> bf16 cast of three arrays + bucket-cursor init, one launch.
// ---------------------------------------------------------------------------
__global__ void cast3_kernel(const float* __restrict__ a, const float* __restrict__ b,
                             const float* __restrict__ c, u16* __restrict__ oa,
                             u16* __restrict__ ob, u16* __restrict__ oc,
                             int na4, int nw4,
                             int* __restrict__ bCursor, int nbuk, int cap) {
    int i = blockIdx.x * blockDim.x + threadIdx.x;
    if (i < nbuk) bCursor[i] = i * cap;          // fixed-stride bucket bases
    const float* in; u16* out; int k;
    if (i < na4)                { in = a; out = oa; k = i; }
    else if (i < na4 + nw4)     { in = b; out = ob; k = i - na4; }
    else if (i < na4 + 2 * nw4) { in = c; out = oc; k = i - na4 - nw4; }
    else return;
    float4 v = *(const float4*)(in + (size_t)k * 4);
    u32 lo = (u32)f2bf(v.x) | ((u32)f2bf(v.y) << 16);
    u32 hi = (u32)f2bf(v.z) | ((u32)f2bf(v.w) << 16);
    *(uint2*)(out + (size_t)k * 4) = make_uint2(lo, hi);
}

// ---------------------------------------------------------------------------
// Partition edges into fixed-stride buckets (bucket b owns temp[b*cap ..)).
// Two-pass per block: LDS hist -> bulk cursor reservation -> LDS scatter.
// Record: .x = dst | srcLocal<<17 (dst < 2^17), .y = weight bits.
// ---------------------------------------------------------------------------
__global__ void partition_kernel(const int* __restrict__ src, const int* __restrict__ dst,
                                 const float* __restrict__ w, int* __restrict__ bucketCursor,
                                 uint2* __restrict__ temp, int E, int nbuk) {
    __shared__ int cnt[1024];
    __shared__ int base[1024];
    int per = (E + gridDim.x - 1) / gridDim.x;
    int lo = blockIdx.x * per;
    int hi = min(E, lo + per);
    for (int i = threadIdx.x; i < nbuk; i += blockDim.x) cnt[i] = 0;
    __syncthreads();
    for (int i = lo + threadIdx.x; i < hi; i += blockDim.x)
        atomicAdd(&cnt[src[i] >> BSH], 1);
    __syncthreads();
    for (int i = threadIdx.x; i < nbuk; i += blockDim.x)
        base[i] = cnt[i] ? atomicAdd(&bucketCursor[i], cnt[i]) : 0;
    __syncthreads();
    for (int i = threadIdx.x; i < nbuk; i += blockDim.x) cnt[i] = 0;
    __syncthreads();
    for (int i = lo + threadIdx.x; i < hi; i += blockDim.x) {
        int s = src[i];
        int b = s >> BSH;
        int off = atomicAdd(&cnt[b], 1);
        temp[base[b] + off] =
            make_uint2((u32)dst[i] | ((u32)(s & BMASK) << 17), __float_as_uint(w[i]));
    }
}

// ---------------------------------------------------------------------------
// Per-bucket CSR finalize. One block per bucket; bucket b owns
// temp[b*cap .. bucketEnd[b]). Emits per-node (start,deg) into rowse and
// node-sorted records into edge[] (same strided window).
// ---------------------------------------------------------------------------
__global__ void bucket_csr(const uint2* __restrict__ temp, const int* __restrict__ bucketEnd,
                           uint2* __restrict__ rowse, uint2* __restrict__ edge,
                           int N, int cap) {
    int b = blockIdx.x;
    int lo = b * cap;
    int hi = bucketEnd[b];
    int t = threadIdx.x;
    __shared__ int deg_l[256];
    __shared__ int sc[256];
    __shared__ int cur[256];
    deg_l[t] = 0;
    __syncthreads();
    for (int i = lo + t; i < hi; i += 256)
        atomicAdd(&deg_l[temp[i].x >> 17], 1);
    __syncthreads();
    int mydeg = deg_l[t];
    sc[t] = mydeg;
    __syncthreads();
    for (int off = 1; off < 256; off <<= 1) {
        int v = (t >= off) ? sc[t - off] : 0;
        __syncthreads();
        sc[t] += v;
        __syncthreads();
    }
    int excl = (t == 0) ? 0 : sc[t - 1];
    int gnode = (b << BSH) + t;
    if (gnode < N) rowse[gnode] = make_uint2((u32)(lo + excl), (u32)mydeg);
    cur[t] = excl;
    __syncthreads();
    for (int i = lo + t; i < hi; i += 256) {
        uint2 r = temp[i];                     // L2-hot
        int p = atomicAdd(&cur[r.x >> 17], 1);
        edge[lo + p] = make_uint2(r.x & 0x1FFFFu, r.y);
    }
}

// ---------------------------------------------------------------------------
// Gather aggregation (bf16): one wave per 2 nodes. readfirstlane on the
// segment bounds makes the inner loop wave-uniform for the compiler:
// edge records -> s_load (scalar cache), gather base -> SGPR, w -> SGPR
// operand of v_fmac. Per edge: ~1 VMEM + ~5 VALU.
// ---------------------------------------------------------------------------
__global__ void aggregate_kernel(const u16* __restrict__ feat,
                                 const uint2* __restrict__ rowse,
                                 const uint2* __restrict__ edge,
                                 u16* __restrict__ neigh, int n) {
    const char* fb = (const char*)feat;
    int wv = blockIdx.x * 4 + (threadIdx.x >> 6);
    int lane = threadIdx.x & 63;
    int node0 = wv * 2;
    if (node0 >= n) return;
    const u32 lo4 = (u32)lane * 4u;
    int nend = min(node0 + 2, n);
    for (int node = node0; node < nend; ++node) {
        uint2 se = rowse[node];
        int beg = __builtin_amdgcn_readfirstlane((int)se.x);
        int deg = __builtin_amdgcn_readfirstlane((int)se.y);
        int end = beg + deg;
        float ax = 0.f, ay = 0.f, ws = 0.f;
        int j = beg;
        for (; j + 3 < end; j += 4) {   // 4 gathers in flight
            uint2 e0 = edge[j], e1 = edge[j + 1], e2 = edge[j + 2], e3 = edge[j + 3];
            float w0 = __uint_as_float(e0.y), w1 = __uint_as_float(e1.y);
            float w2 = __uint_as_float(e2.y), w3 = __uint_as_float(e3.y);
            u32 u0 = *(const u32*)(fb + e0.x * 256u + lo4);
            u32 u1 = *(const u32*)(fb + e1.x * 256u + lo4);
            u32 u2 = *(const u32*)(fb + e2.x * 256u + lo4);
            u32 u3 = *(const u32*)(fb + e3.x * 256u + lo4);
            ax += __uint_as_float(u0 << 16) * w0 + __uint_as_float(u1 << 16) * w1
                + __uint_as_float(u2 << 16) * w2 + __uint_as_float(u3 << 16) * w3;
            ay += __uint_as_float(u0 & 0xFFFF0000u) * w0 + __uint_as_float(u1 & 0xFFFF0000u) * w1
                + __uint_as_float(u2 & 0xFFFF0000u) * w2 + __uint_as_float(u3 & 0xFFFF0000u) * w3;
            ws += w0 + w1 + w2 + w3;
        }
        for (; j < end; ++j) {
            uint2 e0 = edge[j];
            float w0 = __uint_as_float(e0.y);
            u32 u0 = *(const u32*)(fb + e0.x * 256u + lo4);
            ax += __uint_as_float(u0 << 16) * w0;
            ay += __uint_as_float(u0 & 0xFFFF0000u) * w0;
            ws += w0;
        }
        float inv = 1.0f / fmaxf(ws, 1e-12f);
        u32 o = (u32)f2bf(ax * inv) | ((u32)f2bf(ay * inv) << 16);
        *(u32*)(neigh + (size_t)node * D + lane * 2) = o;
    }
}

// ---------------------------------------------------------------------------
// Fused SAGE GEMM, all-bf16 inputs. 256x128 tile/block, 512 threads (8 waves).
// Register-prefetch double buffering. (Unchanged.)
// ---------------------------------------------------------------------------
template <bool NORM>
__global__ void __launch_bounds__(512, 4)
sage_gemm(const u16* __restrict__ axb,
          const u16* __restrict__ aneigh,
          const u16* __restrict__ Wb,      // [128][256] bf16
          const float* __restrict__ bias,  // [128]
          u16* __restrict__ outB,          // NORM=false
          float* __restrict__ outF,        // NORM=true
          int n) {
    __shared__ short As[256][72];   // +8 pad keeps aliasing 2-way (free)
    __shared__ short Bs[128][72];

    const int row0 = blockIdx.x * 256;
    const int tid  = threadIdx.x;
    const int wave = tid >> 6;
    const int lane = tid & 63;
    const int quad = lane >> 4;
    const int l16  = lane & 15;

    f32x4 acc[2][8];
#pragma unroll
    for (int rt = 0; rt < 2; ++rt)
#pragma unroll
        for (int c = 0; c < 8; ++c)
            acc[rt][c] = (f32x4){0.f, 0.f, 0.f, 0.f};

    uint4 pa[4], pb[2];
    auto loadTile = [&](int kc) {
        const u16* asrc = (kc >= 2) ? aneigh : axb;
        const int cbase = (kc & 1) * 64;
#pragma unroll
        for (int i = 0; i < 4; ++i) {
            int e = i * 512 + tid;
            int r = e >> 3;
            int c8 = (e & 7) * 8;
            int row = row0 + r;
            if (row >= n) row = n - 1;       // clamp; garbage rows never stored
            pa[i] = *(const uint4*)(asrc + (size_t)row * D + cbase + c8);
        }
#pragma unroll
        for (int i = 0; i < 2; ++i) {
            int e = i * 512 + tid;
            int r = e >> 3;
            int c8 = (e & 7) * 8;
            pb[i] = *(const uint4*)(Wb + (size_t)r * 256 + kc * 64 + c8);
        }
    };

    loadTile(0);
#pragma unroll
    for (int kc = 0; kc < 4; ++kc) {
#pragma unroll
        for (int i = 0; i < 4; ++i) {
            int e = i * 512 + tid;
            *(uint4*)(&As[e >> 3][(e & 7) * 8]) = pa[i];
        }
#pragma unroll
        for (int i = 0; i < 2; ++i) {
            int e = i * 512 + tid;
            *(uint4*)(&Bs[e >> 3][(e & 7) * 8]) = pb[i];
        }
        __syncthreads();
        if (kc < 3) loadTile(kc + 1);   // overlaps with MFMA below

#pragma unroll
        for (int ks = 0; ks < 2; ++ks) {
            const int koff = ks * 32 + quad * 8;
            bf16x8 a0 = *(const bf16x8*)&As[wave * 32 + l16][koff];
            bf16x8 a1 = *(const bf16x8*)&As[wave * 32 + 16 + l16][koff];
#pragma unroll
            for (int c = 0; c < 8; ++c) {
                bf16x8 b = *(const bf16x8*)&Bs[c * 16 + l16][koff];
                acc[0][c] = __builtin_amdgcn_mfma_f32_16x16x32_bf16(a0, b, acc[0][c], 0, 0, 0);
                acc[1][c] = __builtin_amdgcn_mfma_f32_16x16x32_bf16(a1, b, acc[1][c], 0, 0, 0);
            }
        }
        __syncthreads();
    }

    // Epilogue. C/D layout: col=lane&15, row=quad*4+reg.
    float bvals[8];
#pragma unroll
    for (int c = 0; c < 8; ++c) bvals[c] = bias[c * 16 + l16];

#pragma unroll
    for (int rt = 0; rt < 2; ++rt) {
#pragma unroll
        for (int reg = 0; reg < 4; ++reg) {
            int row = row0 + wave * 32 + rt * 16 + quad * 4 + reg;
            if (row >= n) continue;
            float v[8];
#pragma unroll
            for (int c = 0; c < 8; ++c)
                v[c] = fmaxf(acc[rt][c][reg] + bvals[c], 0.0f);
            if (NORM) {
                float ss = 0.f;
#pragma unroll
                for (int c = 0; c < 8; ++c) ss += v[c] * v[c];
                ss += __shfl_xor(ss, 1);
                ss += __shfl_xor(ss, 2);
                ss += __shfl_xor(ss, 4);
                ss += __shfl_xor(ss, 8);
                float inv = 1.0f / fmaxf(sqrtf(ss), 1e-12f);
                float* orow = outF + (size_t)row * D;
#pragma unroll
                for (int c = 0; c < 8; ++c)
                    orow[c * 16 + l16] = v[c] * inv;
            } else {
                u16* orow = outB + (size_t)row * D;
#pragma unroll
                for (int c = 0; c < 8; ++c)
                    orow[c * 16 + l16] = f2bf(v[c]);
            }
        }
    }
}

extern "C" void kernel_launch(void* const* d_in, const int* in_sizes, int n_in,
                              void* d_out, int out_size, void* d_ws, size_t ws_size,
                              hipStream_t stream) {
    const float* x  = (const float*)d_in[0];
    const int*   ei = (const int*)d_in[1];   // [2, E]: row 0 = src, row 1 = dst
    const float* ew = (const float*)d_in[2];
    const float* W1 = (const float*)d_in[3];
    const float* b1 = (const float*)d_in[4];
    const float* W2 = (const float*)d_in[5];
    const float* b2 = (const float*)d_in[6];
    float* out = (float*)d_out;

    const int E = in_sizes[2];
    const int N = in_sizes[0] / D;
    const int nbuk = (N + BMASK) >> BSH;                 // 391 for N=100000
    const int CAP = ((2 * (E / nbuk + 1) + 1023) / 1024) * 1024;  // 4096: 2x mean, overflow P~0

    const int* src = ei;
    const int* dst = ei + E;

    // workspace layout
    char* p = (char*)d_ws;
    auto alloc = [&](size_t bytes) { char* r = p; p += (bytes + 255) & ~(size_t)255; return r; };
    u16*   xb      = (u16*)  alloc((size_t)N * D * sizeof(u16));          // 25.6 MB
    u16*   hB      = (u16*)  alloc((size_t)N * D * sizeof(u16));          // 25.6 MB
    u16*   neighB  = (u16*)  alloc((size_t)N * D * sizeof(u16));          // 25.6 MB
    uint2* temp    = (uint2*)alloc(((size_t)nbuk * CAP + 64) * 8);        // 12.8 MB
    uint2* edge    = (uint2*)alloc(((size_t)nbuk * CAP + 64) * 8);        // 12.8 MB
    u16*   Wb1     = (u16*)  alloc((size_t)D * 2 * D * sizeof(u16));
    u16*   Wb2     = (u16*)  alloc((size_t)D * 2 * D * sizeof(u16));
    uint2* rowse   = (uint2*)alloc((size_t)N * sizeof(uint2));
    int*   bCursor = (int*)  alloc((size_t)(nbuk + 1) * sizeof(int));

    const int gemmGrid = (N + 255) / 256;
    const int n4 = N * D / 4;
    const int w4 = D * 2 * D / 4;   // 8192
    const int castTotal = n4 + 2 * w4;
    const int aggGrid = ((N + 1) / 2 + 3) / 4;

    // ---- casts + cursor init, then bucket partition + per-bucket CSR ----
    cast3_kernel    <<<(castTotal + 255) / 256, 256, 0, stream>>>(x, W1, W2, xb, Wb1, Wb2,
                                                                  n4, w4, bCursor, nbuk, CAP);
    partition_kernel<<<256, 256, 0, stream>>>(src, dst, ew, bCursor, temp, E, nbuk);
    bucket_csr      <<<nbuk, 256, 0, stream>>>(temp, bCursor, rowse, edge, N, CAP);

    // ---- Layer 1 ----
    aggregate_kernel<<<aggGrid, 256, 0, stream>>>(xb, rowse, edge, neighB, N);
    sage_gemm<false><<<gemmGrid, 512, 0, stream>>>(xb, neighB, Wb1, b1, hB, nullptr, N);

    // ---- Layer 2 (normalize fused into epilogue) ----
    aggregate_kernel<<<aggGrid, 256, 0, stream>>>(hB, rowse, edge, neighB, N);
    sage_gemm<true><<<gemmGrid, 512, 0, stream>>>(hB, neighB, Wb2, b2, nullptr, out, N);
}